// Round 2
// baseline (805.019 us; speedup 1.0000x reference)
//
#include <hip/hip_runtime.h>
#include <math.h>

// Problem constants
#define B 8
#define M 1024
#define D 768
#define NEXP 64
#define P 16
#define H 1536
#define S 1024          // n*p slots
#define EPS_NORM 1e-6f
#define EPS_LN   1e-5f

typedef unsigned short u16;
typedef __attribute__((ext_vector_type(8))) short bf16x8;
typedef __attribute__((ext_vector_type(4))) float f32x4;

__device__ __forceinline__ u16 f2bf(float f) {
    union { float f; unsigned u; } v; v.f = f;
    unsigned r = v.u + 0x7FFFu + ((v.u >> 16) & 1u);   // RNE
    return (u16)(r >> 16);
}

__device__ __forceinline__ float gelu_exact(float x) {
    return 0.5f * x * (1.0f + erff(x * 0.70710678118654752440f));
}

#define GLL16(g, l) __builtin_amdgcn_global_load_lds( \
    (const __attribute__((address_space(1))) void*)(g), \
    (__attribute__((address_space(3))) void*)(l), 16, 0, 0)

// ---------------------------------------------------------------------------
// MFMA GEMM core (NT, both operands bf16 k-contiguous): 128x128 tile, BK=32.
// Double-buffered: stage t+1 while computing t; ONE barrier per K-step.
__device__ __forceinline__ void mfma_core_128(const u16* __restrict__ Ag,
                                              const u16* __restrict__ Bg,
                                              int K, u16* As, u16* Bs,
                                              f32x4 (&acc)[4][4]) {
    const int t    = threadIdx.x;
    const int lane = t & 63;
    const int wave = t >> 6;
    const int wr   = (wave >> 1) << 6;
    const int wc   = (wave & 1) << 6;
    const int quad = lane >> 4;
    const int l16  = lane & 15;
    const u16* ga0 = Ag + (size_t)(t >> 2) * K + (t & 3) * 8;
    const u16* ga1 = ga0 + (size_t)64 * K;
    const u16* gb0 = Bg + (size_t)(t >> 2) * K + (t & 3) * 8;
    const u16* gb1 = gb0 + (size_t)64 * K;
    u16* la0 = As + t * 8;
    u16* lb0 = Bs + t * 8;
    const u16* arp = As + (wr + l16) * 32 + quad * 8;
    const u16* brp = Bs + (wc + l16) * 32 + quad * 8;
    GLL16(ga0, la0);
    GLL16(ga1, la0 + 2048);
    GLL16(gb0, lb0);
    GLL16(gb1, lb0 + 2048);
    int cur = 0;
    for (int k0 = 0; k0 < K; k0 += 32) {
        __syncthreads();
        const int nxt = cur ^ 1;
        if (k0 + 32 < K) {
            GLL16(ga0 + k0 + 32, la0 + nxt * 4096);
            GLL16(ga1 + k0 + 32, la0 + nxt * 4096 + 2048);
            GLL16(gb0 + k0 + 32, lb0 + nxt * 4096);
            GLL16(gb1 + k0 + 32, lb0 + nxt * 4096 + 2048);
        }
        const u16* ar = arp + cur * 4096;
        const u16* br = brp + cur * 4096;
        bf16x8 af[4], bfr[4];
#pragma unroll
        for (int i = 0; i < 4; ++i) af[i]  = *(const bf16x8*)(ar + i * 512);
#pragma unroll
        for (int j = 0; j < 4; ++j) bfr[j] = *(const bf16x8*)(br + j * 512);
#pragma unroll
        for (int i = 0; i < 4; ++i)
#pragma unroll
            for (int j = 0; j < 4; ++j)
                acc[i][j] = __builtin_amdgcn_mfma_f32_16x16x32_bf16(af[i], bfr[j], acc[i][j], 0, 0, 0);
        cur = nxt;
    }
}

// ---------------------------------------------------------------------------
// MFMA GEMM core, A bf16 NT (k-contig), B fp32 NATIVE k-major [K][ldb].
// Double-buffered; B issue-early / cvt-write-late (T14 split).
__device__ __forceinline__ void mfma_core_bf32(const u16* __restrict__ Ag, int K,
                                               const float* __restrict__ Bg, int ldb,
                                               u16* As, u16* Bs,
                                               f32x4 (&acc)[4][4]) {
    const int t    = threadIdx.x;
    const int lane = t & 63;
    const int wave = t >> 6;
    const int wr   = (wave >> 1) << 6;
    const int wc   = (wave & 1) << 6;
    const int quad = lane >> 4;
    const int l16  = lane & 15;
    const u16* ga0 = Ag + (size_t)(t >> 2) * K + (t & 3) * 8;
    const u16* ga1 = ga0 + (size_t)64 * K;
    u16* la0 = As + t * 8;
    const int bcol = t & 127;
    const int kq   = (t >> 7) << 4;
    const float* bg0 = Bg + (size_t)kq * ldb + bcol;
    u16* lb = Bs + bcol * 40 + kq;
    const u16* arp = As + (wr + l16) * 32 + quad * 8;
    const u16* brp = Bs + (wc + l16) * 40 + quad * 8;
    GLL16(ga0, la0);
    GLL16(ga1, la0 + 2048);
    {
        float f[16];
#pragma unroll
        for (int i = 0; i < 16; ++i) f[i] = bg0[(size_t)i * ldb];
#pragma unroll
        for (int i = 0; i < 4; ++i) {
            ushort4 o;
            o.x = f2bf(f[i*4 + 0]); o.y = f2bf(f[i*4 + 1]);
            o.z = f2bf(f[i*4 + 2]); o.w = f2bf(f[i*4 + 3]);
            *(ushort4*)(lb + i * 4) = o;
        }
    }
    int cur = 0;
    for (int k0 = 0; k0 < K; k0 += 32) {
        __syncthreads();
        const int nxt = cur ^ 1;
        const bool pf = (k0 + 32 < K);
        float f[16];
        if (pf) {
            GLL16(ga0 + k0 + 32, la0 + nxt * 4096);
            GLL16(ga1 + k0 + 32, la0 + nxt * 4096 + 2048);
            const float* bg = bg0 + (size_t)(k0 + 32) * ldb;
#pragma unroll
            for (int i = 0; i < 16; ++i) f[i] = bg[(size_t)i * ldb];
        }
        const u16* ar = arp + cur * 4096;
        const u16* br = brp + cur * 5120;
        bf16x8 af[4], bfr[4];
#pragma unroll
        for (int i = 0; i < 4; ++i) af[i]  = *(const bf16x8*)(ar + i * 512);
#pragma unroll
        for (int j = 0; j < 4; ++j) bfr[j] = *(const bf16x8*)(br + j * 640);
#pragma unroll
        for (int i = 0; i < 4; ++i)
#pragma unroll
            for (int j = 0; j < 4; ++j)
                acc[i][j] = __builtin_amdgcn_mfma_f32_16x16x32_bf16(af[i], bfr[j], acc[i][j], 0, 0, 0);
        if (pf) {
            u16* lbn = lb + nxt * 5120;
#pragma unroll
            for (int i = 0; i < 4; ++i) {
                ushort4 o;
                o.x = f2bf(f[i*4 + 0]); o.y = f2bf(f[i*4 + 1]);
                o.z = f2bf(f[i*4 + 2]); o.w = f2bf(f[i*4 + 3]);
                *(ushort4*)(lbn + i * 4) = o;
            }
        }
        cur = nxt;
    }
}

#define EPI_VARS \
    const int t = threadIdx.x; const int lane = t & 63; const int wave = t >> 6; \
    const int wr = (wave >> 1) << 6; const int wc = (wave & 1) << 6; \
    const int quad = lane >> 4; const int l16 = lane & 15; (void)t;

#define ACC_INIT \
    f32x4 acc[4][4]; \
    _Pragma("unroll") for (int i = 0; i < 4; ++i) \
    _Pragma("unroll") for (int j = 0; j < 4; ++j) acc[i][j] = (f32x4){0.f, 0.f, 0.f, 0.f};

// ---------------------------------------------------------------------------
// Fused prep: xprep (z<8) + phi_norm (z==8)
__global__ __launch_bounds__(256) void prep_fused_kernel(const float* __restrict__ x,
                                                         const float* __restrict__ phi,
                                                         u16* __restrict__ xb,
                                                         u16* __restrict__ xT,
                                                         u16* __restrict__ phinb) {
    if (blockIdx.z == 8) {
        int bid = blockIdx.y * 12 + blockIdx.x;     // 0..191
        if (bid >= 48) return;
        int pos = bid * 256 + threadIdx.x;          // 0..P*D-1
        float ss = 0.f;
#pragma unroll 4
        for (int nn = 0; nn < NEXP; ++nn) {
            float v = phi[nn * (P*D) + pos];
            ss += v * v;
        }
        float r = rsqrtf(ss + EPS_NORM);
#pragma unroll 4
        for (int nn = 0; nn < NEXP; ++nn)
            phinb[nn * (P*D) + pos] = f2bf(phi[nn * (P*D) + pos] * r);
        return;
    }
    __shared__ float tile[64][65];
    int b = blockIdx.z;
    int m0 = blockIdx.y * 64, d0 = blockIdx.x * 64;
    int tt = threadIdx.x;
    int rr = tt >> 4, c4 = (tt & 15) * 4;
#pragma unroll
    for (int i = 0; i < 4; ++i) {
        int m = m0 + rr + i * 16;
        float4 v = *(const float4*)(x + ((size_t)b * M + m) * D + d0 + c4);
        tile[rr + i*16][c4 + 0] = v.x;
        tile[rr + i*16][c4 + 1] = v.y;
        tile[rr + i*16][c4 + 2] = v.z;
        tile[rr + i*16][c4 + 3] = v.w;
        ushort4 o;
        o.x = f2bf(v.x); o.y = f2bf(v.y); o.z = f2bf(v.z); o.w = f2bf(v.w);
        *(ushort4*)(xb + ((size_t)b * M + m) * D + d0 + c4) = o;
    }
    __syncthreads();
    int cr = tt >> 4, r4 = (tt & 15) * 4;
#pragma unroll
    for (int i = 0; i < 4; ++i) {
        int crow = cr + i * 16;
        ushort4 o;
        o.x = f2bf(tile[r4 + 0][crow]);
        o.y = f2bf(tile[r4 + 1][crow]);
        o.z = f2bf(tile[r4 + 2][crow]);
        o.w = f2bf(tile[r4 + 3][crow]);
        *(ushort4*)(xT + ((size_t)b * D + d0 + crow) * M + m0 + r4) = o;
    }
}

// ---------------------------------------------------------------------------
// GEMM kernels
// ---------------------------------------------------------------------------

__global__ __launch_bounds__(256) void gemm_logits_mfma(const u16* __restrict__ xb,
                                                        const u16* __restrict__ phinb,
                                                        float* __restrict__ logits) {
    __shared__ __align__(16) u16 As[8192], Bs[8192];
    ACC_INIT;
    const int row0 = blockIdx.y * 128, col0 = blockIdx.x * 128;
    mfma_core_128(xb + (size_t)row0 * D, phinb + (size_t)col0 * D, D, As, Bs, acc);
    EPI_VARS;
#pragma unroll
    for (int i = 0; i < 4; ++i)
#pragma unroll
        for (int j = 0; j < 4; ++j) {
            int col = col0 + wc + j*16 + l16;
#pragma unroll
            for (int r = 0; r < 4; ++r) {
                int row = row0 + wr + i*16 + quad*4 + r;
                logits[(size_t)row * S + col] = acc[i][j][r];
            }
        }
}

__global__ __launch_bounds__(256) void gemm_dispatch_mfma(const u16* __restrict__ DT,
                                                          const u16* __restrict__ xT,
                                                          float* __restrict__ Xs) {
    __shared__ __align__(16) u16 As[8192], Bs[8192];
    ACC_INIT;
    const int b = blockIdx.z;
    const int row0 = blockIdx.y * 128, col0 = blockIdx.x * 128;
    mfma_core_128(DT + ((size_t)b * S + row0) * M,
                  xT + ((size_t)b * D + col0) * M, M, As, Bs, acc);
    EPI_VARS;
#pragma unroll
    for (int i = 0; i < 4; ++i)
#pragma unroll
        for (int j = 0; j < 4; ++j) {
            int col = col0 + wc + j*16 + l16;
#pragma unroll
            for (int r = 0; r < 4; ++r) {
                int row = row0 + wr + i*16 + quad*4 + r;
                Xs[((size_t)b * S + row) * D + col] = acc[i][j][r];
            }
        }
}

__global__ __launch_bounds__(256) void gemm_mlp1_mfma(const u16* __restrict__ hdnE,
                                                      const float* __restrict__ w1,
                                                      const float* __restrict__ b1,
                                                      u16* __restrict__ h1) {
    __shared__ __align__(16) u16 As[8192], Bs[10240];
    ACC_INIT;
    const int n = blockIdx.z;
    const int col0 = blockIdx.x * 128;
    mfma_core_bf32(hdnE + (size_t)n * 128 * D, D,
                   w1 + (size_t)n * D * H + col0, H, As, Bs, acc);
    EPI_VARS;
#pragma unroll
    for (int i = 0; i < 4; ++i)
#pragma unroll
        for (int j = 0; j < 4; ++j) {
            int h = col0 + wc + j*16 + l16;
            float bias = b1[n * H + h];
#pragma unroll
            for (int r = 0; r < 4; ++r) {
                int row = wr + i*16 + quad*4 + r;
                h1[((size_t)n * 128 + row) * H + h] = f2bf(gelu_exact(acc[i][j][r] + bias));
            }
        }
}

__global__ __launch_bounds__(256) void gemm_mlp2_mfma(const u16* __restrict__ h1,
                                                      const float* __restrict__ w2,
                                                      const float* __restrict__ b2,
                                                      u16* __restrict__ YsT) {
    __shared__ __align__(16) u16 As[8192], Bs[10240];
    ACC_INIT;
    const int n = blockIdx.z;
    const int col0 = blockIdx.x * 128;
    mfma_core_bf32(h1 + (size_t)n * 128 * H, H,
                   w2 + (size_t)n * H * D + col0, D, As, Bs, acc);
    EPI_VARS;
#pragma unroll
    for (int i = 0; i < 4; ++i)
#pragma unroll
        for (int j = 0; j < 4; ++j) {
            int d = col0 + wc + j*16 + l16;
            float bias = b2[n * D + d];
            int bb = ((wr + i*16) >> 4);
            int p0 = quad * 4;
            ushort4 o;
            o.x = f2bf(acc[i][j][0] + bias);
            o.y = f2bf(acc[i][j][1] + bias);
            o.z = f2bf(acc[i][j][2] + bias);
            o.w = f2bf(acc[i][j][3] + bias);
            *(ushort4*)(YsT + ((size_t)bb * D + d) * S + n * P + p0) = o;
        }
}

__global__ __launch_bounds__(256) void gemm_combine_mfma(const u16* __restrict__ Cb,
                                                         const u16* __restrict__ YsT,
                                                         float* __restrict__ out) {
    __shared__ __align__(16) u16 As[8192], Bs[8192];
    ACC_INIT;
    const int b = blockIdx.z;
    const int row0 = blockIdx.y * 128, col0 = blockIdx.x * 128;
    mfma_core_128(Cb + ((size_t)b * M + row0) * S,
                  YsT + ((size_t)b * D + col0) * S, S, As, Bs, acc);
    EPI_VARS;
#pragma unroll
    for (int i = 0; i < 4; ++i)
#pragma unroll
        for (int j = 0; j < 4; ++j) {
            int col = col0 + wc + j*16 + l16;
#pragma unroll
            for (int r = 0; r < 4; ++r) {
                int row = row0 + wr + i*16 + quad*4 + r;
                out[((size_t)b * M + row) * D + col] = acc[i][j][r];
            }
        }
}

// ---------------------------------------------------------------------------
// Fused row-softmax + column-softmax partials: reads logits ONCE.
// Grid: 256 blocks; block c2 = b*32 + mgrp covers rows mgrp*32..+31 of batch b.
// Each of 4 waves processes 8 rows; per-lane 16 columns get online (m,l).
__global__ __launch_bounds__(256) void smcol_kernel(const float* __restrict__ logits,
                                                    u16* __restrict__ Cb,
                                                    float* __restrict__ pm,
                                                    float* __restrict__ pl) {
    __shared__ float lm[3][1024], ll[3][1024];     // waves 1..3 partials (24 KB)
    const int c2   = blockIdx.x;
    const int b    = c2 >> 5;
    const int mgrp = c2 & 31;
    const int t    = threadIdx.x;
    const int w    = t >> 6;
    const int lane = t & 63;
    float cm[16], cl[16];
#pragma unroll
    for (int i = 0; i < 16; ++i) { cm[i] = -INFINITY; cl[i] = 0.f; }
    const size_t rbase = (size_t)(b * 1024 + mgrp * 32 + w * 8) * 1024;
    const float* Lb = logits + rbase;
    u16* Cbb = Cb + rbase;
    for (int r = 0; r < 8; ++r) {
        const float* row = Lb + (size_t)r * 1024;
        float4 v[4];
#pragma unroll
        for (int q = 0; q < 4; ++q)
            v[q] = *(const float4*)(row + q * 256 + lane * 4);
        float mx = -INFINITY;
#pragma unroll
        for (int q = 0; q < 4; ++q)
            mx = fmaxf(mx, fmaxf(fmaxf(v[q].x, v[q].y), fmaxf(v[q].z, v[q].w)));
#pragma unroll
        for (int o = 1; o < 64; o <<= 1) mx = fmaxf(mx, __shfl_xor(mx, o));
        float4 e[4]; float sum = 0.f;
#pragma unroll
        for (int q = 0; q < 4; ++q) {
            e[q].x = expf(v[q].x - mx); e[q].y = expf(v[q].y - mx);
            e[q].z = expf(v[q].z - mx); e[q].w = expf(v[q].w - mx);
            sum += e[q].x + e[q].y + e[q].z + e[q].w;
        }
#pragma unroll
        for (int o = 1; o < 64; o <<= 1) sum += __shfl_xor(sum, o);
        float inv = 1.f / sum;
#pragma unroll
        for (int q = 0; q < 4; ++q) {
            ushort4 o4;
            o4.x = f2bf(e[q].x * inv); o4.y = f2bf(e[q].y * inv);
            o4.z = f2bf(e[q].z * inv); o4.w = f2bf(e[q].w * inv);
            *(ushort4*)(Cbb + (size_t)r * 1024 + q * 256 + lane * 4) = o4;
        }
        // online column update (raw logits)
#pragma unroll
        for (int q = 0; q < 4; ++q) {
            float vv[4] = {v[q].x, v[q].y, v[q].z, v[q].w};
#pragma unroll
            for (int j = 0; j < 4; ++j) {
                int idx = q * 4 + j;
                float nm = fmaxf(cm[idx], vv[j]);
                cl[idx] = cl[idx] * expf(cm[idx] - nm) + expf(vv[j] - nm);
                cm[idx] = nm;
            }
        }
    }
    if (w > 0) {
#pragma unroll
        for (int q = 0; q < 4; ++q)
#pragma unroll
            for (int j = 0; j < 4; ++j) {
                int col = q * 256 + lane * 4 + j;
                lm[w - 1][col] = cm[q * 4 + j];
                ll[w - 1][col] = cl[q * 4 + j];
            }
    }
    __syncthreads();
    if (w == 0) {
#pragma unroll
        for (int q = 0; q < 4; ++q)
#pragma unroll
            for (int j = 0; j < 4; ++j) {
                int idx = q * 4 + j;
                int col = q * 256 + lane * 4 + j;
#pragma unroll
                for (int wv = 0; wv < 3; ++wv) {
                    float m2 = lm[wv][col], l2 = ll[wv][col];
                    float nm = fmaxf(cm[idx], m2);
                    cl[idx] = cl[idx] * expf(cm[idx] - nm) + l2 * expf(m2 - nm);
                    cm[idx] = nm;
                }
                pm[mgrp * 8192 + b * 1024 + col] = cm[idx];
                pl[mgrp * 8192 + b * 1024 + col] = cl[idx];
            }
    }
}

// ---------------------------------------------------------------------------
// Fused colsm_combine + normalize + transpose -> DT[b][s][m] bf16.
// Grid (16, 4, 8): block covers 64 s-cols x 256 m-rows (4 sub-tiles of 64x64).
__global__ __launch_bounds__(256) void dtc_kernel(const float* __restrict__ logits,
                                                  const float* __restrict__ pm,
                                                  const float* __restrict__ pl,
                                                  u16* __restrict__ DT) {
    __shared__ float tile[64][65];
    __shared__ float fmS[64], flS[64];
    const int b  = blockIdx.z;
    const int s0 = blockIdx.x * 64;
    const int m0base = blockIdx.y * 256;
    const int tt = threadIdx.x;
    if (tt < 64) {
        int col = b * 1024 + s0 + tt;
        float mx = -INFINITY;
#pragma unroll 8
        for (int c = 0; c < 32; ++c) mx = fmaxf(mx, pm[c * 8192 + col]);
        float l = 0.f;
#pragma unroll 8
        for (int c = 0; c < 32; ++c) l += pl[c * 8192 + col] * expf(pm[c * 8192 + col] - mx);
        fmS[tt] = mx;
        flS[tt] = 1.f / l;
    }
    __syncthreads();
    const int rr = tt >> 4, c4 = (tt & 15) * 4;
    const int cr = tt >> 4, r4 = (tt & 15) * 4;
    for (int sub = 0; sub < 4; ++sub) {
        const int m0 = m0base + sub * 64;
        float fm0 = fmS[c4 + 0], fm1 = fmS[c4 + 1], fm2 = fmS[c4 + 2], fm3 = fmS[c4 + 3];
        float fl0 = flS[c4 + 0], fl1 = flS[c4 + 1], fl2 = flS[c4 + 2], fl3 = flS[c4 + 3];
#pragma unroll
        for (int i = 0; i < 4; ++i) {
            float4 v = *(const float4*)(logits + ((size_t)b * M + m0 + rr + i*16) * S + s0 + c4);
            tile[rr + i*16][c4 + 0] = expf(v.x - fm0) * fl0;
            tile[rr + i*16][c4 + 1] = expf(v.y - fm1) * fl1;
            tile[rr + i*16][c4 + 2] = expf(v.z - fm2) * fl2;
            tile[rr + i*16][c4 + 3] = expf(v.w - fm3) * fl3;
        }
        __syncthreads();
#pragma unroll
        for (int i = 0; i < 4; ++i) {
            int crow = cr + i * 16;       // s index within tile
            ushort4 o;
            o.x = f2bf(tile[r4 + 0][crow]);
            o.y = f2bf(tile[r4 + 1][crow]);
            o.z = f2bf(tile[r4 + 2][crow]);
            o.w = f2bf(tile[r4 + 3][crow]);
            *(ushort4*)(DT + ((size_t)b * S + s0 + crow) * M + m0 + r4) = o;
        }
        __syncthreads();
    }
}

// LayerNorm rows of Xs (fp32) -> hdnE bf16 in expert-major layout [n][b*16+p][d]
__global__ __launch_bounds__(256) void layernorm_kernel(const float* __restrict__ Xs,
                                                        const float* __restrict__ g,
                                                        const float* __restrict__ bt,
                                                        u16* __restrict__ hdnE) {
    __shared__ float rs[4], rq[4];
    int row = blockIdx.x;                  // b*1024 + n*16 + p
    int b = row >> 10;
    int n = (row >> 4) & (NEXP - 1);
    int p = row & 15;
    const float* rp = Xs + (size_t)row * D;
    u16* op = hdnE + ((size_t)n * 128 + b * 16 + p) * D;
    int t = threadIdx.x;
    float x0 = rp[t], x1 = rp[t + 256], x2 = rp[t + 512];
    float s  = x0 + x1 + x2;
    float sq = x0*x0 + x1*x1 + x2*x2;
#pragma unroll
    for (int o = 1; o < 64; o <<= 1) { s += __shfl_xor(s, o); sq += __shfl_xor(sq, o); }
    if ((t & 63) == 0) { rs[t >> 6] = s; rq[t >> 6] = sq; }
    __syncthreads();
    s  = rs[0] + rs[1] + rs[2] + rs[3];
    sq = rq[0] + rq[1] + rq[2] + rq[3];
    float mu  = s * (1.f / D);
    float var = sq * (1.f / D) - mu * mu;
    float inv = rsqrtf(var + EPS_LN);
    const float* gn = g  + n * D;
    const float* bn = bt + n * D;
    op[t]       = f2bf((x0 - mu) * inv * gn[t]       + bn[t]);
    op[t + 256] = f2bf((x1 - mu) * inv * gn[t + 256] + bn[t + 256]);
    op[t + 512] = f2bf((x2 - mu) * inv * gn[t + 512] + bn[t + 512]);
}

// ---------------------------------------------------------------------------
extern "C" void kernel_launch(void* const* d_in, const int* in_sizes, int n_in,
                              void* d_out, int out_size, void* d_ws, size_t ws_size,
                              hipStream_t stream) {
    const float* x    = (const float*)d_in[0];
    const float* phi  = (const float*)d_in[1];
    const float* ln_g = (const float*)d_in[2];
    const float* ln_b = (const float*)d_in[3];
    const float* w1   = (const float*)d_in[4];
    const float* b1   = (const float*)d_in[5];
    const float* w2   = (const float*)d_in[6];
    const float* b2   = (const float*)d_in[7];
    float* out = (float*)d_out;

    char* ws = (char*)d_ws;
    float* logits = (float*)(ws + 0);               // 33.6 MB (reused as Xs fp32)
    u16*   Cb     = (u16*)(ws + 33554432);          // 16.8 MB
    u16*   xb     = (u16*)(ws + 50331648);          // 12.6 MB (xb+DT reused as h1)
    u16*   DT     = (u16*)(ws + 62914560);          // 16.8 MB
    u16*   xTb    = (u16*)(ws + 79691776);          // 12.6 MB (reused as YsT)
    u16*   phinb  = (u16*)(ws + 92274688);          //  1.6 MB
    u16*   hdnE   = (u16*)(ws + 93847552);          // 12.6 MB
    float* pm     = (float*)(ws + 106430464);       //  1.0 MB (32 chunks)
    float* pl     = (float*)(ws + 107479040);       //  1.0 MB
    float* Xs     = logits;                         // overlay (logits dead by then)
    u16*   h1     = xb;                             // overlay (xb+DT dead by then)
    u16*   YsT    = xTb;                            // overlay (xTb dead by then)

    // --- prep (fused) ---
    prep_fused_kernel<<<dim3(12, 16, 9), 256, 0, stream>>>(x, phi, xb, xTb, phinb);

    // --- routing ---
    gemm_logits_mfma<<<dim3(8, 64), 256, 0, stream>>>(xb, phinb, logits);
    smcol_kernel<<<256, 256, 0, stream>>>(logits, Cb, pm, pl);
    dtc_kernel<<<dim3(16, 4, B), 256, 0, stream>>>(logits, pm, pl, DT);

    // --- dispatch ---
    gemm_dispatch_mfma<<<dim3(6, 8, B), 256, 0, stream>>>(DT, xTb, Xs);
    layernorm_kernel<<<B * S, 256, 0, stream>>>(Xs, ln_g, ln_b, hdnE);

    // --- expert MLP ---
    gemm_mlp1_mfma<<<dim3(12, 1, NEXP), 256, 0, stream>>>(hdnE, w1, b1, h1);
    gemm_mlp2_mfma<<<dim3(6, 1, NEXP), 256, 0, stream>>>(h1, w2, b2, YsT);

    // --- combine ---
    gemm_combine_mfma<<<dim3(6, 8, B), 256, 0, stream>>>(Cb, YsT, out);
}

// Round 3
// 795.142 us; speedup vs baseline: 1.0124x; 1.0124x over previous
//
#include <hip/hip_runtime.h>
#include <math.h>

// Problem constants
#define B 8
#define M 1024
#define D 768
#define NEXP 64
#define P 16
#define H 1536
#define S 1024          // n*p slots
#define EPS_NORM 1e-6f
#define EPS_LN   1e-5f

typedef unsigned short u16;
typedef __attribute__((ext_vector_type(8))) short bf16x8;
typedef __attribute__((ext_vector_type(4))) float f32x4;

__device__ __forceinline__ u16 f2bf(float f) {
    union { float f; unsigned u; } v; v.f = f;
    unsigned r = v.u + 0x7FFFu + ((v.u >> 16) & 1u);   // RNE
    return (u16)(r >> 16);
}

__device__ __forceinline__ float gelu_exact(float x) {
    return 0.5f * x * (1.0f + erff(x * 0.70710678118654752440f));
}

#define GLL16(g, l) __builtin_amdgcn_global_load_lds( \
    (const __attribute__((address_space(1))) void*)(g), \
    (__attribute__((address_space(3))) void*)(l), 16, 0, 0)

// ---------------------------------------------------------------------------
// MFMA GEMM core (NT, both bf16 k-contiguous): 128x128 tile, BK=32.
// TRIPLE-buffered LDS, 2-deep global_load_lds prefetch, counted vmcnt
// (never drains to 0 mid-loop), ONE raw s_barrier per K-step.
// As/Bs = 3 x 4096 u16 each (24 KB each).
__device__ __forceinline__ void mfma_core_128(const u16* __restrict__ Ag,
                                              const u16* __restrict__ Bg,
                                              int K, u16* As, u16* Bs,
                                              f32x4 (&acc)[4][4]) {
    const int t    = threadIdx.x;
    const int lane = t & 63;
    const int wave = t >> 6;
    const int wr   = (wave >> 1) << 6;
    const int wc   = (wave & 1) << 6;
    const int quad = lane >> 4;
    const int l16  = lane & 15;
    const u16* ga0 = Ag + (size_t)(t >> 2) * K + (t & 3) * 8;
    const u16* ga1 = ga0 + (size_t)64 * K;
    const u16* gb0 = Bg + (size_t)(t >> 2) * K + (t & 3) * 8;
    const u16* gb1 = gb0 + (size_t)64 * K;
    u16 *sa0 = As + t * 8, *sa1 = sa0 + 4096, *sa2 = sa0 + 8192;
    u16 *sb0 = Bs + t * 8, *sb1 = sb0 + 4096, *sb2 = sb0 + 8192;
    const u16 *ra0 = As + (wr + l16) * 32 + quad * 8;
    const u16 *ra1 = ra0 + 4096, *ra2 = ra0 + 8192;
    const u16 *rb0 = Bs + (wc + l16) * 32 + quad * 8;
    const u16 *rb1 = rb0 + 4096, *rb2 = rb0 + 8192;
    // prologue: stage k=0 -> buf0, k=32 -> buf1 (8 loads in flight)
    GLL16(ga0, sa0); GLL16(ga1, sa0 + 2048);
    GLL16(gb0, sb0); GLL16(gb1, sb0 + 2048);
    if (K > 32) {
        GLL16(ga0 + 32, sa1); GLL16(ga1 + 32, sa1 + 2048);
        GLL16(gb0 + 32, sb1); GLL16(gb1 + 32, sb1 + 2048);
    }
    for (int k0 = 0; k0 < K; k0 += 32) {
        const int rem = ((K - k0) >> 5) - 1;     // K-steps remaining after this
        // wait for THIS tile's 4 loads only; next tile's 4 stay in flight
        if (rem >= 1) asm volatile("s_waitcnt vmcnt(4)" ::: "memory");
        else          asm volatile("s_waitcnt vmcnt(0)" ::: "memory");
        __builtin_amdgcn_s_barrier();
        __builtin_amdgcn_sched_barrier(0);
        if (rem >= 2) {                          // stage t+2 (post-barrier: safe)
            GLL16(ga0 + k0 + 64, sa2); GLL16(ga1 + k0 + 64, sa2 + 2048);
            GLL16(gb0 + k0 + 64, sb2); GLL16(gb1 + k0 + 64, sb2 + 2048);
        }
        bf16x8 af[4], bfr[4];
#pragma unroll
        for (int i = 0; i < 4; ++i) af[i]  = *(const bf16x8*)(ra0 + i * 512);
#pragma unroll
        for (int j = 0; j < 4; ++j) bfr[j] = *(const bf16x8*)(rb0 + j * 512);
#pragma unroll
        for (int i = 0; i < 4; ++i)
#pragma unroll
            for (int j = 0; j < 4; ++j)
                acc[i][j] = __builtin_amdgcn_mfma_f32_16x16x32_bf16(af[i], bfr[j], acc[i][j], 0, 0, 0);
        // rotate buffers (named ptrs: no runtime indexing -> no scratch)
        u16* tw;
        tw = sa0; sa0 = sa1; sa1 = sa2; sa2 = tw;
        tw = sb0; sb0 = sb1; sb1 = sb2; sb2 = tw;
        const u16* tr;
        tr = ra0; ra0 = ra1; ra1 = ra2; ra2 = tr;
        tr = rb0; rb0 = rb1; rb1 = rb2; rb2 = tr;
    }
}

// ---------------------------------------------------------------------------
// MFMA GEMM core, A bf16 NT (k-contig, triple-buffered via global_load_lds),
// B fp32 NATIVE k-major [K][ldb]: issue-early regs -> cvt -> ds_write-late,
// double-buffered [col][k] stride-40. Counted vmcnt; one barrier per step.
// As = 3 x 4096 u16 (24 KB), Bs = 2 x 5120 u16 (20 KB).
__device__ __forceinline__ void mfma_core_bf32(const u16* __restrict__ Ag, int K,
                                               const float* __restrict__ Bg, int ldb,
                                               u16* As, u16* Bs,
                                               f32x4 (&acc)[4][4]) {
    const int t    = threadIdx.x;
    const int lane = t & 63;
    const int wave = t >> 6;
    const int wr   = (wave >> 1) << 6;
    const int wc   = (wave & 1) << 6;
    const int quad = lane >> 4;
    const int l16  = lane & 15;
    const u16* ga0 = Ag + (size_t)(t >> 2) * K + (t & 3) * 8;
    const u16* ga1 = ga0 + (size_t)64 * K;
    u16 *sa0 = As + t * 8, *sa1 = sa0 + 4096, *sa2 = sa0 + 8192;
    const int bcol = t & 127;
    const int kq   = (t >> 7) << 4;
    const float* bg0 = Bg + (size_t)kq * ldb + bcol;
    u16 *bw0 = Bs + bcol * 40 + kq;          // B write base, buf0
    u16 *bw1 = bw0 + 5120;
    const u16 *rbA = Bs + (wc + l16) * 40 + quad * 8;   // B read, buf0
    const u16 *rbB = rbA + 5120;
    const u16 *ra0 = As + (wr + l16) * 32 + quad * 8;
    const u16 *ra1 = ra0 + 4096, *ra2 = ra0 + 8192;
    // prologue: B(0) reg loads, A(0)/A(1) stages, cvt+write B(0)->Bs0
    {
        float f[16];
#pragma unroll
        for (int i = 0; i < 16; ++i) f[i] = bg0[(size_t)i * ldb];
        GLL16(ga0, sa0); GLL16(ga1, sa0 + 2048);
        if (K > 32) { GLL16(ga0 + 32, sa1); GLL16(ga1 + 32, sa1 + 2048); }
#pragma unroll
        for (int i = 0; i < 4; ++i) {
            ushort4 o;
            o.x = f2bf(f[i*4 + 0]); o.y = f2bf(f[i*4 + 1]);
            o.z = f2bf(f[i*4 + 2]); o.w = f2bf(f[i*4 + 3]);
            *(ushort4*)(bw0 + i * 4) = o;
        }
    }
    const u16* rbc = rbA;   // current B read buf
    u16*       bwn = bw1;   // next B write buf
    const u16* rbo = rbB;
    u16*       bwo = bw0;
    for (int k0 = 0; k0 < K; k0 += 32) {
        const int rem = ((K - k0) >> 5) - 1;
        // wait A(t) (leave A(t+1) in flight); drain my ds_writes pre-barrier
        if (rem >= 1) asm volatile("s_waitcnt vmcnt(2) lgkmcnt(0)" ::: "memory");
        else          asm volatile("s_waitcnt vmcnt(0) lgkmcnt(0)" ::: "memory");
        __builtin_amdgcn_s_barrier();
        __builtin_amdgcn_sched_barrier(0);
        float f[16];
        if (rem >= 1) {
            // B(t+1) reg loads FIRST (so compiler's wait for them = vmcnt(2),
            // keeping the younger A GLLs in flight)
            const float* bg = bg0 + (size_t)(k0 + 32) * ldb;
#pragma unroll
            for (int i = 0; i < 16; ++i) f[i] = bg[(size_t)i * ldb];
        }
        if (rem >= 2) {                          // A(t+2), post-barrier
            GLL16(ga0 + k0 + 64, sa2); GLL16(ga1 + k0 + 64, sa2 + 2048);
        }
        bf16x8 af[4], bfr[4];
#pragma unroll
        for (int i = 0; i < 4; ++i) af[i]  = *(const bf16x8*)(ra0 + i * 512);
#pragma unroll
        for (int j = 0; j < 4; ++j) bfr[j] = *(const bf16x8*)(rbc + j * 640);
#pragma unroll
        for (int i = 0; i < 4; ++i)
#pragma unroll
            for (int j = 0; j < 4; ++j)
                acc[i][j] = __builtin_amdgcn_mfma_f32_16x16x32_bf16(af[i], bfr[j], acc[i][j], 0, 0, 0);
        if (rem >= 1) {                          // write-late B(t+1)
#pragma unroll
            for (int i = 0; i < 4; ++i) {
                ushort4 o;
                o.x = f2bf(f[i*4 + 0]); o.y = f2bf(f[i*4 + 1]);
                o.z = f2bf(f[i*4 + 2]); o.w = f2bf(f[i*4 + 3]);
                *(ushort4*)(bwn + i * 4) = o;
            }
        }
        // rotate A, swap B
        u16* tw;
        tw = sa0; sa0 = sa1; sa1 = sa2; sa2 = tw;
        const u16* tr;
        tr = ra0; ra0 = ra1; ra1 = ra2; ra2 = tr;
        tr = rbc; rbc = rbo; rbo = tr;
        tw = bwn; bwn = bwo; bwo = tw;
    }
}

#define EPI_VARS \
    const int t = threadIdx.x; const int lane = t & 63; const int wave = t >> 6; \
    const int wr = (wave >> 1) << 6; const int wc = (wave & 1) << 6; \
    const int quad = lane >> 4; const int l16 = lane & 15; (void)t;

#define ACC_INIT \
    f32x4 acc[4][4]; \
    _Pragma("unroll") for (int i = 0; i < 4; ++i) \
    _Pragma("unroll") for (int j = 0; j < 4; ++j) acc[i][j] = (f32x4){0.f, 0.f, 0.f, 0.f};

// ---------------------------------------------------------------------------
// Fused prep: xprep (z<8) + phi_norm (z==8)
__global__ __launch_bounds__(256) void prep_fused_kernel(const float* __restrict__ x,
                                                         const float* __restrict__ phi,
                                                         u16* __restrict__ xb,
                                                         u16* __restrict__ xT,
                                                         u16* __restrict__ phinb) {
    if (blockIdx.z == 8) {
        int bid = blockIdx.y * 12 + blockIdx.x;     // 0..191
        if (bid >= 48) return;
        int pos = bid * 256 + threadIdx.x;          // 0..P*D-1
        float ss = 0.f;
#pragma unroll 4
        for (int nn = 0; nn < NEXP; ++nn) {
            float v = phi[nn * (P*D) + pos];
            ss += v * v;
        }
        float r = rsqrtf(ss + EPS_NORM);
#pragma unroll 4
        for (int nn = 0; nn < NEXP; ++nn)
            phinb[nn * (P*D) + pos] = f2bf(phi[nn * (P*D) + pos] * r);
        return;
    }
    __shared__ float tile[64][65];
    int b = blockIdx.z;
    int m0 = blockIdx.y * 64, d0 = blockIdx.x * 64;
    int tt = threadIdx.x;
    int rr = tt >> 4, c4 = (tt & 15) * 4;
#pragma unroll
    for (int i = 0; i < 4; ++i) {
        int m = m0 + rr + i * 16;
        float4 v = *(const float4*)(x + ((size_t)b * M + m) * D + d0 + c4);
        tile[rr + i*16][c4 + 0] = v.x;
        tile[rr + i*16][c4 + 1] = v.y;
        tile[rr + i*16][c4 + 2] = v.z;
        tile[rr + i*16][c4 + 3] = v.w;
        ushort4 o;
        o.x = f2bf(v.x); o.y = f2bf(v.y); o.z = f2bf(v.z); o.w = f2bf(v.w);
        *(ushort4*)(xb + ((size_t)b * M + m) * D + d0 + c4) = o;
    }
    __syncthreads();
    int cr = tt >> 4, r4 = (tt & 15) * 4;
#pragma unroll
    for (int i = 0; i < 4; ++i) {
        int crow = cr + i * 16;
        ushort4 o;
        o.x = f2bf(tile[r4 + 0][crow]);
        o.y = f2bf(tile[r4 + 1][crow]);
        o.z = f2bf(tile[r4 + 2][crow]);
        o.w = f2bf(tile[r4 + 3][crow]);
        *(ushort4*)(xT + ((size_t)b * D + d0 + crow) * M + m0 + r4) = o;
    }
}

// ---------------------------------------------------------------------------
// GEMM kernels
// ---------------------------------------------------------------------------

__global__ __launch_bounds__(256) void gemm_logits_mfma(const u16* __restrict__ xb,
                                                        const u16* __restrict__ phinb,
                                                        float* __restrict__ logits) {
    __shared__ __align__(16) u16 As[12288], Bs[12288];
    ACC_INIT;
    const int row0 = blockIdx.y * 128, col0 = blockIdx.x * 128;
    mfma_core_128(xb + (size_t)row0 * D, phinb + (size_t)col0 * D, D, As, Bs, acc);
    EPI_VARS;
#pragma unroll
    for (int i = 0; i < 4; ++i)
#pragma unroll
        for (int j = 0; j < 4; ++j) {
            int col = col0 + wc + j*16 + l16;
#pragma unroll
            for (int r = 0; r < 4; ++r) {
                int row = row0 + wr + i*16 + quad*4 + r;
                logits[(size_t)row * S + col] = acc[i][j][r];
            }
        }
}

__global__ __launch_bounds__(256) void gemm_dispatch_mfma(const u16* __restrict__ DT,
                                                          const u16* __restrict__ xT,
                                                          float* __restrict__ Xs) {
    __shared__ __align__(16) u16 As[12288], Bs[12288];
    ACC_INIT;
    const int b = blockIdx.z;
    const int row0 = blockIdx.y * 128, col0 = blockIdx.x * 128;
    mfma_core_128(DT + ((size_t)b * S + row0) * M,
                  xT + ((size_t)b * D + col0) * M, M, As, Bs, acc);
    EPI_VARS;
#pragma unroll
    for (int i = 0; i < 4; ++i)
#pragma unroll
        for (int j = 0; j < 4; ++j) {
            int col = col0 + wc + j*16 + l16;
#pragma unroll
            for (int r = 0; r < 4; ++r) {
                int row = row0 + wr + i*16 + quad*4 + r;
                Xs[((size_t)b * S + row) * D + col] = acc[i][j][r];
            }
        }
}

__global__ __launch_bounds__(256) void gemm_mlp1_mfma(const u16* __restrict__ hdnE,
                                                      const float* __restrict__ w1,
                                                      const float* __restrict__ b1,
                                                      u16* __restrict__ h1) {
    __shared__ __align__(16) u16 As[12288], Bs[10240];
    ACC_INIT;
    const int n = blockIdx.z;
    const int col0 = blockIdx.x * 128;
    mfma_core_bf32(hdnE + (size_t)n * 128 * D, D,
                   w1 + (size_t)n * D * H + col0, H, As, Bs, acc);
    EPI_VARS;
#pragma unroll
    for (int i = 0; i < 4; ++i)
#pragma unroll
        for (int j = 0; j < 4; ++j) {
            int h = col0 + wc + j*16 + l16;
            float bias = b1[n * H + h];
#pragma unroll
            for (int r = 0; r < 4; ++r) {
                int row = wr + i*16 + quad*4 + r;
                h1[((size_t)n * 128 + row) * H + h] = f2bf(gelu_exact(acc[i][j][r] + bias));
            }
        }
}

__global__ __launch_bounds__(256) void gemm_mlp2_mfma(const u16* __restrict__ h1,
                                                      const float* __restrict__ w2,
                                                      const float* __restrict__ b2,
                                                      u16* __restrict__ YsT) {
    __shared__ __align__(16) u16 As[12288], Bs[10240];
    ACC_INIT;
    const int n = blockIdx.z;
    const int col0 = blockIdx.x * 128;
    mfma_core_bf32(h1 + (size_t)n * 128 * H, H,
                   w2 + (size_t)n * H * D + col0, D, As, Bs, acc);
    EPI_VARS;
#pragma unroll
    for (int i = 0; i < 4; ++i)
#pragma unroll
        for (int j = 0; j < 4; ++j) {
            int d = col0 + wc + j*16 + l16;
            float bias = b2[n * D + d];
            int bb = ((wr + i*16) >> 4);
            int p0 = quad * 4;
            ushort4 o;
            o.x = f2bf(acc[i][j][0] + bias);
            o.y = f2bf(acc[i][j][1] + bias);
            o.z = f2bf(acc[i][j][2] + bias);
            o.w = f2bf(acc[i][j][3] + bias);
            *(ushort4*)(YsT + ((size_t)bb * D + d) * S + n * P + p0) = o;
        }
}

__global__ __launch_bounds__(256) void gemm_combine_mfma(const u16* __restrict__ Cb,
                                                         const u16* __restrict__ YsT,
                                                         float* __restrict__ out) {
    __shared__ __align__(16) u16 As[12288], Bs[12288];
    ACC_INIT;
    const int b = blockIdx.z;
    const int row0 = blockIdx.y * 128, col0 = blockIdx.x * 128;
    mfma_core_128(Cb + ((size_t)b * M + row0) * S,
                  YsT + ((size_t)b * D + col0) * S, S, As, Bs, acc);
    EPI_VARS;
#pragma unroll
    for (int i = 0; i < 4; ++i)
#pragma unroll
        for (int j = 0; j < 4; ++j) {
            int col = col0 + wc + j*16 + l16;
#pragma unroll
            for (int r = 0; r < 4; ++r) {
                int row = row0 + wr + i*16 + quad*4 + r;
                out[((size_t)b * M + row) * D + col] = acc[i][j][r];
            }
        }
}

// ---------------------------------------------------------------------------
// Fused row-softmax + column-softmax partials: reads logits ONCE.
__global__ __launch_bounds__(256) void smcol_kernel(const float* __restrict__ logits,
                                                    u16* __restrict__ Cb,
                                                    float* __restrict__ pm,
                                                    float* __restrict__ pl) {
    __shared__ float lm[3][1024], ll[3][1024];     // waves 1..3 partials (24 KB)
    const int c2   = blockIdx.x;
    const int b    = c2 >> 5;
    const int mgrp = c2 & 31;
    const int t    = threadIdx.x;
    const int w    = t >> 6;
    const int lane = t & 63;
    float cm[16], cl[16];
#pragma unroll
    for (int i = 0; i < 16; ++i) { cm[i] = -INFINITY; cl[i] = 0.f; }
    const size_t rbase = (size_t)(b * 1024 + mgrp * 32 + w * 8) * 1024;
    const float* Lb = logits + rbase;
    u16* Cbb = Cb + rbase;
    for (int r = 0; r < 8; ++r) {
        const float* row = Lb + (size_t)r * 1024;
        float4 v[4];
#pragma unroll
        for (int q = 0; q < 4; ++q)
            v[q] = *(const float4*)(row + q * 256 + lane * 4);
        float mx = -INFINITY;
#pragma unroll
        for (int q = 0; q < 4; ++q)
            mx = fmaxf(mx, fmaxf(fmaxf(v[q].x, v[q].y), fmaxf(v[q].z, v[q].w)));
#pragma unroll
        for (int o = 1; o < 64; o <<= 1) mx = fmaxf(mx, __shfl_xor(mx, o));
        float4 e[4]; float sum = 0.f;
#pragma unroll
        for (int q = 0; q < 4; ++q) {
            e[q].x = expf(v[q].x - mx); e[q].y = expf(v[q].y - mx);
            e[q].z = expf(v[q].z - mx); e[q].w = expf(v[q].w - mx);
            sum += e[q].x + e[q].y + e[q].z + e[q].w;
        }
#pragma unroll
        for (int o = 1; o < 64; o <<= 1) sum += __shfl_xor(sum, o);
        float inv = 1.f / sum;
#pragma unroll
        for (int q = 0; q < 4; ++q) {
            ushort4 o4;
            o4.x = f2bf(e[q].x * inv); o4.y = f2bf(e[q].y * inv);
            o4.z = f2bf(e[q].z * inv); o4.w = f2bf(e[q].w * inv);
            *(ushort4*)(Cbb + (size_t)r * 1024 + q * 256 + lane * 4) = o4;
        }
#pragma unroll
        for (int q = 0; q < 4; ++q) {
            float vv[4] = {v[q].x, v[q].y, v[q].z, v[q].w};
#pragma unroll
            for (int j = 0; j < 4; ++j) {
                int idx = q * 4 + j;
                float nm = fmaxf(cm[idx], vv[j]);
                cl[idx] = cl[idx] * expf(cm[idx] - nm) + expf(vv[j] - nm);
                cm[idx] = nm;
            }
        }
    }
    if (w > 0) {
#pragma unroll
        for (int q = 0; q < 4; ++q)
#pragma unroll
            for (int j = 0; j < 4; ++j) {
                int col = q * 256 + lane * 4 + j;
                lm[w - 1][col] = cm[q * 4 + j];
                ll[w - 1][col] = cl[q * 4 + j];
            }
    }
    __syncthreads();
    if (w == 0) {
#pragma unroll
        for (int q = 0; q < 4; ++q)
#pragma unroll
            for (int j = 0; j < 4; ++j) {
                int idx = q * 4 + j;
                int col = q * 256 + lane * 4 + j;
#pragma unroll
                for (int wv = 0; wv < 3; ++wv) {
                    float m2 = lm[wv][col], l2 = ll[wv][col];
                    float nm = fmaxf(cm[idx], m2);
                    cl[idx] = cl[idx] * expf(cm[idx] - nm) + l2 * expf(m2 - nm);
                    cm[idx] = nm;
                }
                pm[mgrp * 8192 + b * 1024 + col] = cm[idx];
                pl[mgrp * 8192 + b * 1024 + col] = cl[idx];
            }
    }
}

// ---------------------------------------------------------------------------
// Fused colsm_combine + normalize + transpose -> DT[b][s][m] bf16.
__global__ __launch_bounds__(256) void dtc_kernel(const float* __restrict__ logits,
                                                  const float* __restrict__ pm,
                                                  const float* __restrict__ pl,
                                                  u16* __restrict__ DT) {
    __shared__ float tile[64][65];
    __shared__ float fmS[64], flS[64];
    const int b  = blockIdx.z;
    const int s0 = blockIdx.x * 64;
    const int m0base = blockIdx.y * 256;
    const int tt = threadIdx.x;
    if (tt < 64) {
        int col = b * 1024 + s0 + tt;
        float mx = -INFINITY;
#pragma unroll 8
        for (int c = 0; c < 32; ++c) mx = fmaxf(mx, pm[c * 8192 + col]);
        float l = 0.f;
#pragma unroll 8
        for (int c = 0; c < 32; ++c) l += pl[c * 8192 + col] * expf(pm[c * 8192 + col] - mx);
        fmS[tt] = mx;
        flS[tt] = 1.f / l;
    }
    __syncthreads();
    const int rr = tt >> 4, c4 = (tt & 15) * 4;
    const int cr = tt >> 4, r4 = (tt & 15) * 4;
    for (int sub = 0; sub < 4; ++sub) {
        const int m0 = m0base + sub * 64;
        float fm0 = fmS[c4 + 0], fm1 = fmS[c4 + 1], fm2 = fmS[c4 + 2], fm3 = fmS[c4 + 3];
        float fl0 = flS[c4 + 0], fl1 = flS[c4 + 1], fl2 = flS[c4 + 2], fl3 = flS[c4 + 3];
#pragma unroll
        for (int i = 0; i < 4; ++i) {
            float4 v = *(const float4*)(logits + ((size_t)b * M + m0 + rr + i*16) * S + s0 + c4);
            tile[rr + i*16][c4 + 0] = expf(v.x - fm0) * fl0;
            tile[rr + i*16][c4 + 1] = expf(v.y - fm1) * fl1;
            tile[rr + i*16][c4 + 2] = expf(v.z - fm2) * fl2;
            tile[rr + i*16][c4 + 3] = expf(v.w - fm3) * fl3;
        }
        __syncthreads();
#pragma unroll
        for (int i = 0; i < 4; ++i) {
            int crow = cr + i * 16;       // s index within tile
            ushort4 o;
            o.x = f2bf(tile[r4 + 0][crow]);
            o.y = f2bf(tile[r4 + 1][crow]);
            o.z = f2bf(tile[r4 + 2][crow]);
            o.w = f2bf(tile[r4 + 3][crow]);
            *(ushort4*)(DT + ((size_t)b * S + s0 + crow) * M + m0 + r4) = o;
        }
        __syncthreads();
    }
}

// LayerNorm rows of Xs (fp32) -> hdnE bf16 in expert-major layout [n][b*16+p][d]
__global__ __launch_bounds__(256) void layernorm_kernel(const float* __restrict__ Xs,
                                                        const float* __restrict__ g,
                                                        const float* __restrict__ bt,
                                                        u16* __restrict__ hdnE) {
    __shared__ float rs[4], rq[4];
    int row = blockIdx.x;                  // b*1024 + n*16 + p
    int b = row >> 10;
    int n = (row >> 4) & (NEXP - 1);
    int p = row & 15;
    const float* rp = Xs + (size_t)row * D;
    u16* op = hdnE + ((size_t)n * 128 + b * 16 + p) * D;
    int t = threadIdx.x;
    float x0 = rp[t], x1 = rp[t + 256], x2 = rp[t + 512];
    float s  = x0 + x1 + x2;
    float sq = x0*x0 + x1*x1 + x2*x2;
#pragma unroll
    for (int o = 1; o < 64; o <<= 1) { s += __shfl_xor(s, o); sq += __shfl_xor(sq, o); }
    if ((t & 63) == 0) { rs[t >> 6] = s; rq[t >> 6] = sq; }
    __syncthreads();
    s  = rs[0] + rs[1] + rs[2] + rs[3];
    sq = rq[0] + rq[1] + rq[2] + rq[3];
    float mu  = s * (1.f / D);
    float var = sq * (1.f / D) - mu * mu;
    float inv = rsqrtf(var + EPS_LN);
    const float* gn = g  + n * D;
    const float* bn = bt + n * D;
    op[t]       = f2bf((x0 - mu) * inv * gn[t]       + bn[t]);
    op[t + 256] = f2bf((x1 - mu) * inv * gn[t + 256] + bn[t + 256]);
    op[t + 512] = f2bf((x2 - mu) * inv * gn[t + 512] + bn[t + 512]);
}

// ---------------------------------------------------------------------------
extern "C" void kernel_launch(void* const* d_in, const int* in_sizes, int n_in,
                              void* d_out, int out_size, void* d_ws, size_t ws_size,
                              hipStream_t stream) {
    const float* x    = (const float*)d_in[0];
    const float* phi  = (const float*)d_in[1];
    const float* ln_g = (const float*)d_in[2];
    const float* ln_b = (const float*)d_in[3];
    const float* w1   = (const float*)d_in[4];
    const float* b1   = (const float*)d_in[5];
    const float* w2   = (const float*)d_in[6];
    const float* b2   = (const float*)d_in[7];
    float* out = (float*)d_out;

    char* ws = (char*)d_ws;
    float* logits = (float*)(ws + 0);               // 33.6 MB (reused as Xs fp32)
    u16*   Cb     = (u16*)(ws + 33554432);          // 16.8 MB
    u16*   xb     = (u16*)(ws + 50331648);          // 12.6 MB (xb+DT reused as h1)
    u16*   DT     = (u16*)(ws + 62914560);          // 16.8 MB
    u16*   xTb    = (u16*)(ws + 79691776);          // 12.6 MB (reused as YsT)
    u16*   phinb  = (u16*)(ws + 92274688);          //  1.6 MB
    u16*   hdnE   = (u16*)(ws + 93847552);          // 12.6 MB
    float* pm     = (float*)(ws + 106430464);       //  1.0 MB (32 chunks)
    float* pl     = (float*)(ws + 107479040);       //  1.0 MB
    float* Xs     = logits;                         // overlay (logits dead by then)
    u16*   h1     = xb;                             // overlay (xb+DT dead by then)
    u16*   YsT    = xTb;                            // overlay (xTb dead by then)

    // --- prep (fused) ---
    prep_fused_kernel<<<dim3(12, 16, 9), 256, 0, stream>>>(x, phi, xb, xTb, phinb);

    // --- routing ---
    gemm_logits_mfma<<<dim3(8, 64), 256, 0, stream>>>(xb, phinb, logits);
    smcol_kernel<<<256, 256, 0, stream>>>(logits, Cb, pm, pl);
    dtc_kernel<<<dim3(16, 4, B), 256, 0, stream>>>(logits, pm, pl, DT);

    // --- dispatch ---
    gemm_dispatch_mfma<<<dim3(6, 8, B), 256, 0, stream>>>(DT, xTb, Xs);
    layernorm_kernel<<<B * S, 256, 0, stream>>>(Xs, ln_g, ln_b, hdnE);

    // --- expert MLP ---
    gemm_mlp1_mfma<<<dim3(12, 1, NEXP), 256, 0, stream>>>(hdnE, w1, b1, h1);
    gemm_mlp2_mfma<<<dim3(6, 1, NEXP), 256, 0, stream>>>(h1, w2, b2, YsT);

    // --- combine ---
    gemm_combine_mfma<<<dim3(6, 8, B), 256, 0, stream>>>(Cb, YsT, out);
}